// Round 9
// baseline (387.677 us; speedup 1.0000x reference)
//
#include <hip/hip_runtime.h>
#include <math.h>

#define S_LEN 2048
#define D_MODEL 1024
#define NH 16
#define DK 64
#define BATCH 4

// log2(10000)/64
#define ROPE_L2F 0.20762050593046014f
// 0.125 * log2(e): folds 1/sqrt(dk) and exp->exp2 conversion into Q
#define QSCALE 0.18033688011112042f

typedef __attribute__((ext_vector_type(8))) short bf16x8;
typedef __attribute__((ext_vector_type(4))) short short4v;
typedef __attribute__((ext_vector_type(2))) short short2v;
typedef __attribute__((ext_vector_type(4))) float f32x4;

__device__ inline short f2bf(float f) {            // RNE fp32 -> bf16 bits
    unsigned u = __builtin_bit_cast(unsigned, f);
    unsigned r = u + 0x7FFFu + ((u >> 16) & 1u);
    return (short)(r >> 16);
}

// packed fp32x2 -> bf16x2 (RNE), single VALU op
__device__ inline unsigned cvt_pk_bf16(float lo, float hi) {
    unsigned r;
    asm("v_cvt_pk_bf16_f32 %0, %1, %2" : "=v"(r) : "v"(lo), "v"(hi));
    return r;
}

// async global->LDS, 16B per lane; lds base must be wave-uniform.
__device__ inline void load_lds16(const void* g, void* l) {
    __builtin_amdgcn_global_load_lds(
        (const __attribute__((address_space(1))) unsigned int*)g,
        (__attribute__((address_space(3))) unsigned int*)l, 16, 0, 0);
}

// ---------------------------------------------------------------------------
// One-time fp32 -> bf16 conversions.
// ---------------------------------------------------------------------------
__global__ __launch_bounds__(256) void conv_bf16(
    const float* __restrict__ src, short* __restrict__ dst, int n)
{
    int i = (blockIdx.x * 256 + threadIdx.x) * 8;
    if (i >= n) return;
    float4 a = *(const float4*)&src[i];
    float4 b = *(const float4*)&src[i + 4];
    short h[8] = { f2bf(a.x), f2bf(a.y), f2bf(a.z), f2bf(a.w),
                   f2bf(b.x), f2bf(b.y), f2bf(b.z), f2bf(b.w) };
    *(bf16x8*)&dst[i] = *(bf16x8*)h;
}

__global__ __launch_bounds__(256) void conv_w4(
    const float* __restrict__ Wq, const float* __restrict__ Wk,
    const float* __restrict__ Wv, const float* __restrict__ Wo,
    short* __restrict__ dst)
{
    const float* srcs[4] = { Wq, Wk, Wv, Wo };
    const float* s = srcs[blockIdx.y];
    short* d = dst + (size_t)blockIdx.y * (D_MODEL * D_MODEL);
    int i = (blockIdx.x * 256 + threadIdx.x) * 8;
    float4 a = *(const float4*)&s[i];
    float4 b = *(const float4*)&s[i + 4];
    short h[8] = { f2bf(a.x), f2bf(a.y), f2bf(a.z), f2bf(a.w),
                   f2bf(b.x), f2bf(b.y), f2bf(b.z), f2bf(b.w) };
    *(bf16x8*)&d[i] = *(bf16x8*)h;
}

// ---------------------------------------------------------------------------
// RoPE cos/sin table: cst[si*32 + f] = (cos, sin) of tp[si] * theta^(-2f/64).
// ---------------------------------------------------------------------------
__global__ __launch_bounds__(256) void rope_tab(
    const int* __restrict__ tp, float2* __restrict__ cst)
{
    int idx = blockIdx.x * 256 + threadIdx.x;      // 65536 entries
    int si = idx >> 5;
    int f  = idx & 31;
    float pos = (float)tp[si];
    float freq = exp2f(-(float)(2 * f) * ROPE_L2F);
    float s, c;
    __sincosf(pos * freq, &s, &c);
    cst[idx] = make_float2(c, s);
}

// ---------------------------------------------------------------------------
// bf16 MFMA GEMM main loop (m97-style): 128x128 tile, 4 waves 2x2.
// TWO BK=32 k-steps double-buffered per barrier pair (round-6 win, ~20us):
// As/Bs are [2][128][32]; 8 global_load_lds stage k0 and k0+32, ONE
// __syncthreads, compute both, ONE trailing __syncthreads. Staging
// geometry/swizzle per buffer identical to the verified BK=32 version:
// LDS unpadded [128][32] shorts, 16B chunks XOR-swizzled
// (phys = chunk ^ (row&3)) so frag ds_read_b128 is <=4-way.
// ---------------------------------------------------------------------------
#define PROJ_PROLOGUE()                                                      \
    __shared__ short As[2][128][32];                                         \
    __shared__ short Bs[2][128][32];                                         \
    const int m0 = blockIdx.y * 128;                                         \
    const int n0 = blockIdx.x * 128;                                         \
    const int tid = threadIdx.x;                                             \
    const int lane = tid & 63;                                               \
    const int wave = tid >> 6;                                               \
    const int quad = lane >> 4;                                              \
    const int l16 = lane & 15;                                               \
    const int wr = (wave >> 1) * 64;                                         \
    const int wc = (wave & 1) * 64;                                          \
    const int srow = wave * 32 + (lane >> 2);                                \
    const int schunk = (lane & 3) ^ ((lane >> 2) & 3);                       \
    const short* agp = &A[(size_t)(m0 + srow) * D_MODEL + schunk * 8];       \
    const short* bgp = &Bw[(size_t)(n0 + srow) * D_MODEL + schunk * 8];      \
    const int fchunk = quad ^ (l16 & 3);                                     \
    f32x4 acc[4][4] = {};                                                    \
    for (int k0 = 0; k0 < D_MODEL; k0 += 64) {                               \
        _Pragma("unroll")                                                    \
        for (int bb = 0; bb < 2; ++bb) {                                     \
            const short* ag = agp + bb * 32;                                 \
            const short* bg = bgp + bb * 32;                                 \
            load_lds16(ag, &As[bb][wave * 32][0]);                           \
            load_lds16(ag + 16 * D_MODEL, &As[bb][wave * 32 + 16][0]);       \
            load_lds16(bg, &Bs[bb][wave * 32][0]);                           \
            load_lds16(bg + 16 * D_MODEL, &Bs[bb][wave * 32 + 16][0]);       \
        }                                                                    \
        agp += 64; bgp += 64;                                                \
        __syncthreads();                                                     \
        _Pragma("unroll")                                                    \
        for (int bb = 0; bb < 2; ++bb) {                                     \
            bf16x8 a_h[4], b_h[4];                                           \
            _Pragma("unroll")                                                \
            for (int t = 0; t < 4; ++t) {                                    \
                a_h[t] = *(const bf16x8*)                                    \
                    &As[bb][wr + t * 16 + l16][fchunk * 8];                  \
                b_h[t] = *(const bf16x8*)                                    \
                    &Bs[bb][wc + t * 16 + l16][fchunk * 8];                  \
            }                                                                \
            _Pragma("unroll")                                                \
            for (int mt = 0; mt < 4; ++mt)                                   \
                _Pragma("unroll")                                            \
                for (int nt = 0; nt < 4; ++nt)                               \
                    acc[mt][nt] = __builtin_amdgcn_mfma_f32_16x16x32_bf16(   \
                        a_h[mt], b_h[nt], acc[mt][nt], 0, 0, 0);             \
        }                                                                    \
        __syncthreads();                                                     \
    }

// ---------------------------------------------------------------------------
// Fused QKV projection: C = x (8192x1024) @ [Wq;Wk;Wv]^T (1024x3072).
// ---------------------------------------------------------------------------
__global__ __launch_bounds__(256) void proj_qkv(
    const short* __restrict__ A, const short* __restrict__ Bw,
    const float2* __restrict__ cst,
    short* __restrict__ Qo, short* __restrict__ Ko, short* __restrict__ Vo)
{
    PROJ_PROLOGUE()

    const int which = n0 >> 10;                    // 0=Q 1=K 2=V
    short* __restrict__ outp = (which == 0) ? Qo : (which == 1) ? Ko : Vo;
    const float scale = (which == 0) ? QSCALE : 1.0f;
    const int nbase = n0 & (D_MODEL - 1);

#pragma unroll
    for (int mt = 0; mt < 4; ++mt) {
#pragma unroll
        for (int r = 0; r < 4; ++r) {
            const int row = m0 + wr + mt * 16 + quad * 4 + r;
            const int bi = row >> 11;
            const int si = row & (S_LEN - 1);
#pragma unroll
            for (int nt = 0; nt < 4; ++nt) {
                const int col = nbase + wc + nt * 16 + l16;
                const int head = col >> 6;
                const int tloc = col & 63;
                float v = acc[mt][nt][r];
                float res;
                if (which < 2) {
                    float partner = __shfl_xor(v, 1);
                    float xe = (lane & 1) ? partner : v;
                    float xo = (lane & 1) ? v : partner;
                    float2 cs = cst[si * 32 + (tloc >> 1)];
                    res = ((lane & 1) ? (cs.y * xe + cs.x * xo)
                                      : (cs.x * xe - cs.y * xo)) * scale;
                } else {
                    res = v;
                }
                outp[(((size_t)bi * NH + head) * S_LEN + si) * DK + tloc] =
                    f2bf(res);
            }
        }
    }
}

// ---------------------------------------------------------------------------
// Output projection: out = attnO (8192x1024) @ Wo^T, fp32 row-major.
// ---------------------------------------------------------------------------
__global__ __launch_bounds__(256) void proj_out(
    const short* __restrict__ A, const short* __restrict__ Bw,
    float* __restrict__ outf)
{
    PROJ_PROLOGUE()

#pragma unroll
    for (int mt = 0; mt < 4; ++mt) {
#pragma unroll
        for (int r = 0; r < 4; ++r) {
            const int row = m0 + wr + mt * 16 + quad * 4 + r;
#pragma unroll
            for (int nt = 0; nt < 4; ++nt) {
                int col = n0 + wc + nt * 16 + l16;
                outf[(size_t)row * D_MODEL + col] = acc[mt][nt][r];
            }
        }
    }
}

// ---------------------------------------------------------------------------
// MFMA flash causal attention — Bq=64, grid-doubled for TLP.
// Round-4/6 state: 512 blocks = 2/CU, 2 waves/SIMD, all pipes idle (Mfma 9 /
// VALU 41 / HBM 3 / Occ 11) — latency-bound, occupancy bounded by GRID.
// Round-5 lesson: per-wave state can't shrink below ~100 VGPR (64 => remat).
// Fix: 4 waves x 16 q-rows, grid (16,64)=1024 blocks. Per-wave state halves
// naturally (Qf 8 + sT 16 + o 16 + Kf 32 + V 8 ~= 115 VGPR); launch_bounds
// (256,4) caps at 128 => 4 blocks/CU, 16 waves/CU (2x round-4 TLP).
// K dbuf dropped (reload per tile; L2-resident via XCD grouping + TLP hides).
// LDS 27.6KB (Vt[2] dbuf + Ps[64]); one barrier/tile, hidden by cross-block
// overlap. Balanced pairing over 32 q-tiles: bx = 31-pair then pair => 33
// tiles/block uniform. XCD mapping: linear id % 8 == gx&7 == head-group.
// Bq=Bk=64 => only the last tile (t==bx) masks; no divergence elsewhere.
// Kept: lane-local defer-max (THR=8), lane-partial l, cvt_pk P-packing.
// ---------------------------------------------------------------------------
#define PADS 72

__global__ __launch_bounds__(256, 4) void attn_bf16(
    const short* __restrict__ Q, const short* __restrict__ K,
    const short* __restrict__ V, short* __restrict__ O)
{
    __shared__ short Vt[2][64][PADS];  // V tile transposed [d][k], dbuf
    __shared__ short Ps[64][PADS];     // P rows (4 waves x 16), wave-private

    const int gx = blockIdx.x;                     // [0,16)
    const int gy = blockIdx.y;                     // [0,64)
    const int bh   = (gx & 7) * 8 + (gy >> 3);     // head-group pinned to XCD
    const int pair = (gx >> 3) * 8 + (gy & 7);     // [0,16)

    const int tid = threadIdx.x;
    const int wave = tid >> 6;
    const int lane = tid & 63;
    const int quad = lane >> 4;
    const int l16 = lane & 15;

    const short* Kb = K + (size_t)bh * S_LEN * DK;
    const short* Vb = V + (size_t)bh * S_LEN * DK;

    // V staging geometry (transpose via short2): 256 threads, 64k x 64d
    const int kp2 = (tid & 31) * 2;
    const int db = (tid >> 5) * 8;

    const int bi = bh >> 4;
    const int head = bh & 15;

    for (int half = 0; half < 2; ++half) {
        const int bx = half ? pair : (31 - pair);  // q-tile in [0,32)
        const int qbase = bx * 64 + wave * 16;

        // Q fragments straight from global (wave-private rows)
        bf16x8 Qf[2];
#pragma unroll
        for (int c = 0; c < 2; ++c)
            Qf[c] = *(const bf16x8*)
                &Q[((size_t)bh * S_LEN + qbase + l16) * DK + c * 32 + quad * 8];

        // preload V tile 0 into regs
        bf16x8 v0 = *(const bf16x8*)&Vb[(size_t)kp2 * DK + db];
        bf16x8 v1 = *(const bf16x8*)&Vb[(size_t)(kp2 + 1) * DK + db];

        float m_i = -1e30f;
        float l_i = 0.0f;               // LANE-PARTIAL; reduced in epilogue
        f32x4 o[4] = {};

        const int ktiles = bx + 1;
        for (int t = 0; t < ktiles; ++t) {
            const int k0 = t * 64;
            const int buf = t & 1;

            // ---- commit prefetched V regs to Vt[buf] ----
#pragma unroll
            for (int i = 0; i < 8; ++i) {
                short2v p; p.x = v0[i]; p.y = v1[i];
                *(short2v*)&Vt[buf][db + i][kp2] = p;
            }
            __syncthreads();            // dbuf: safe (sync t-1 separates reuse)

            // ---- prefetch V tile t+1 ----
            if (t + 1 < ktiles) {
                const short* vp = &Vb[(size_t)((t + 1) * 64 + kp2) * DK + db];
                v0 = *(const bf16x8*)vp;
                v1 = *(const bf16x8*)(vp + DK);
            }

            // ---- K frags for this tile (reload; L2-resident, TLP hides) ----
            bf16x8 Kf[4][2];
#pragma unroll
            for (int kt = 0; kt < 4; ++kt)
#pragma unroll
                for (int c = 0; c < 2; ++c)
                    Kf[kt][c] = *(const bf16x8*)
                        &Kb[(size_t)(k0 + kt * 16 + l16) * DK +
                            c * 32 + quad * 8];

            // ---- S^T = K * Q^T ----
            f32x4 sT[4] = {};
#pragma unroll
            for (int c = 0; c < 2; ++c)
#pragma unroll
                for (int kt = 0; kt < 4; ++kt)
                    sT[kt] = __builtin_amdgcn_mfma_f32_16x16x32_bf16(
                        Kf[kt][c], Qf[c], sT[kt], 0, 0, 0);

            const int qg = qbase + l16;
            if (k0 + 63 > qbase) {      // only true on last tile (t == bx)
#pragma unroll
                for (int kt = 0; kt < 4; ++kt)
#pragma unroll
                    for (int r = 0; r < 4; ++r)
                        if (k0 + kt * 16 + quad * 4 + r > qg)
                            sT[kt][r] = -1e30f;
            }

            // per-lane max (no cross-lane in common path)
            float tmax = fmaxf(
                fmaxf(fmaxf(sT[0][0], sT[0][1]), fmaxf(sT[0][2], sT[0][3])),
                fmaxf(fmaxf(fmaxf(sT[1][0], sT[1][1]),
                            fmaxf(sT[1][2], sT[1][3])),
                      fmaxf(fmaxf(fmaxf(sT[2][0], sT[2][1]),
                                  fmaxf(sT[2][2], sT[2][3])),
                            fmaxf(fmaxf(sT[3][0], sT[3][1]),
                                  fmaxf(sT[3][2], sT[3][3])))));
            // defer-max: rescale only if some lane exceeds m+8
            if (!__all(tmax <= m_i + 8.0f)) {
                float tm = fmaxf(tmax, __shfl_xor(tmax, 16));
                tm = fmaxf(tm, __shfl_xor(tm, 32));
                float mnew = fmaxf(m_i, tm);
                float alpha = exp2f(m_i - mnew);
                m_i = mnew;
                l_i *= alpha;
#pragma unroll
                for (int dt = 0; dt < 4; ++dt) {
                    o[dt][0] *= alpha; o[dt][1] *= alpha;
                    o[dt][2] *= alpha; o[dt][3] *= alpha;
                }
            }
            const float mn = m_i;
            float rs = 0.0f;
            const int prow = wave * 16 + l16;
#pragma unroll
            for (int kt = 0; kt < 4; ++kt) {
                float p0 = exp2f(sT[kt][0] - mn);
                float p1 = exp2f(sT[kt][1] - mn);
                float p2 = exp2f(sT[kt][2] - mn);
                float p3 = exp2f(sT[kt][3] - mn);
                rs += (p0 + p1) + (p2 + p3);
                uint2 uu;
                uu.x = cvt_pk_bf16(p0, p1);
                uu.y = cvt_pk_bf16(p2, p3);
                *(uint2*)&Ps[prow][kt * 16 + quad * 4] = uu;
            }
            l_i += rs;                  // lane-partial accumulate

            // ---- O^T += V^T P^T ----
            bf16x8 Pf[2];
#pragma unroll
            for (int c = 0; c < 2; ++c)
                Pf[c] = *(const bf16x8*)
                    &Ps[wave * 16 + l16][c * 32 + quad * 8];
#pragma unroll
            for (int c = 0; c < 2; ++c)
#pragma unroll
                for (int dt = 0; dt < 4; ++dt) {
                    bf16x8 av = *(const bf16x8*)
                        &Vt[buf][dt * 16 + l16][c * 32 + quad * 8];
                    o[dt] = __builtin_amdgcn_mfma_f32_16x16x32_bf16(
                        av, Pf[c], o[dt], 0, 0, 0);
                }
        }
        __syncthreads();   // protect Vt bufs before next half's first commit

        // ---- epilogue: reduce lane-partial l, normalize, write bf16 ----
        float lt = l_i;
        lt += __shfl_xor(lt, 16);
        lt += __shfl_xor(lt, 32);
        const float linv = 1.0f / lt;
        const int q = qbase + l16;
        short* ob = &O[((size_t)bi * S_LEN + q) * D_MODEL + head * DK];
#pragma unroll
        for (int dt = 0; dt < 4; ++dt) {
            short4v h;
            h.x = f2bf(o[dt][0] * linv);
            h.y = f2bf(o[dt][1] * linv);
            h.z = f2bf(o[dt][2] * linv);
            h.w = f2bf(o[dt][3] * linv);
            *(short4v*)&ob[dt * 16 + quad * 4] = h;
        }
    }
}

extern "C" void kernel_launch(void* const* d_in, const int* in_sizes, int n_in,
                              void* d_out, int out_size, void* d_ws, size_t ws_size,
                              hipStream_t stream) {
    const float* x  = (const float*)d_in[0];
    const float* Wq = (const float*)d_in[1];
    const float* Wk = (const float*)d_in[2];
    const float* Wv = (const float*)d_in[3];
    const float* Wo = (const float*)d_in[4];
    const int*   tp = (const int*)d_in[5];
    float* out = (float*)d_out;

    const int n  = BATCH * S_LEN * D_MODEL;       // 8388608
    const int nw = D_MODEL * D_MODEL;             // 1048576
    short* sw   = (short*)d_ws;
    short* xbf  = sw;
    short* Qbf  = sw + (size_t)n;
    short* Kbf  = sw + (size_t)2 * n;
    short* Vbf  = sw + (size_t)3 * n;
    short* Obf  = sw + (size_t)4 * n;
    short* Wqbf = sw + (size_t)5 * n;             // Wq;Wk;Wv contiguous (3072x1024)
    short* Wobf = Wqbf + (size_t)3 * nw;
    // RoPE table overlaid on Obf (dead until attn writes it; stream order
    // guarantees rope_tab -> proj_qkv(read) -> attn(overwrite) -> proj_out).
    float2* cst = (float2*)Obf;                   // 512 KB of the 16.8 MB region

    dim3 blk(256);
    conv_bf16<<<n / (256 * 8), blk, 0, stream>>>(x, xbf, n);
    dim3 gw(nw / (256 * 8), 4);
    conv_w4<<<gw, blk, 0, stream>>>(Wq, Wk, Wv, Wo, Wqbf);
    rope_tab<<<(S_LEN * 32) / 256, blk, 0, stream>>>(tp, cst);

    dim3 gqkv(3 * D_MODEL / 128, (BATCH * S_LEN) / 128);   // (24, 64)
    proj_qkv<<<gqkv, blk, 0, stream>>>(xbf, Wqbf, cst, Qbf, Kbf, Vbf);

    dim3 gattn(16, BATCH * NH);                            // Bq=64, paired
    attn_bf16<<<gattn, blk, 0, stream>>>(Qbf, Kbf, Vbf, Obf);

    dim3 gout(D_MODEL / 128, (BATCH * S_LEN) / 128);       // (8, 64)
    proj_out<<<gout, blk, 0, stream>>>(Obf, Wobf, out);
}

// Round 11
// 343.957 us; speedup vs baseline: 1.1271x; 1.1271x over previous
//
#include <hip/hip_runtime.h>
#include <math.h>

#define S_LEN 2048
#define D_MODEL 1024
#define NH 16
#define DK 64
#define BATCH 4

// log2(10000)/64
#define ROPE_L2F 0.20762050593046014f
// 0.125 * log2(e): folds 1/sqrt(dk) and exp->exp2 conversion into Q
#define QSCALE 0.18033688011112042f

typedef __attribute__((ext_vector_type(8))) short bf16x8;
typedef __attribute__((ext_vector_type(4))) short short4v;
typedef __attribute__((ext_vector_type(2))) short short2v;
typedef __attribute__((ext_vector_type(4))) float f32x4;

__device__ inline short f2bf(float f) {            // RNE fp32 -> bf16 bits
    unsigned u = __builtin_bit_cast(unsigned, f);
    unsigned r = u + 0x7FFFu + ((u >> 16) & 1u);
    return (short)(r >> 16);
}

// packed fp32x2 -> bf16x2 (RNE), single VALU op
__device__ inline unsigned cvt_pk_bf16(float lo, float hi) {
    unsigned r;
    asm("v_cvt_pk_bf16_f32 %0, %1, %2" : "=v"(r) : "v"(lo), "v"(hi));
    return r;
}

// async global->LDS, 16B per lane; lds base must be wave-uniform.
__device__ inline void load_lds16(const void* g, void* l) {
    __builtin_amdgcn_global_load_lds(
        (const __attribute__((address_space(1))) unsigned int*)g,
        (__attribute__((address_space(3))) unsigned int*)l, 16, 0, 0);
}

// ---------------------------------------------------------------------------
// One-time fp32 -> bf16 conversions.
// ---------------------------------------------------------------------------
__global__ __launch_bounds__(256) void conv_bf16(
    const float* __restrict__ src, short* __restrict__ dst, int n)
{
    int i = (blockIdx.x * 256 + threadIdx.x) * 8;
    if (i >= n) return;
    float4 a = *(const float4*)&src[i];
    float4 b = *(const float4*)&src[i + 4];
    short h[8] = { f2bf(a.x), f2bf(a.y), f2bf(a.z), f2bf(a.w),
                   f2bf(b.x), f2bf(b.y), f2bf(b.z), f2bf(b.w) };
    *(bf16x8*)&dst[i] = *(bf16x8*)h;
}

__global__ __launch_bounds__(256) void conv_w4(
    const float* __restrict__ Wq, const float* __restrict__ Wk,
    const float* __restrict__ Wv, const float* __restrict__ Wo,
    short* __restrict__ dst)
{
    const float* srcs[4] = { Wq, Wk, Wv, Wo };
    const float* s = srcs[blockIdx.y];
    short* d = dst + (size_t)blockIdx.y * (D_MODEL * D_MODEL);
    int i = (blockIdx.x * 256 + threadIdx.x) * 8;
    float4 a = *(const float4*)&s[i];
    float4 b = *(const float4*)&s[i + 4];
    short h[8] = { f2bf(a.x), f2bf(a.y), f2bf(a.z), f2bf(a.w),
                   f2bf(b.x), f2bf(b.y), f2bf(b.z), f2bf(b.w) };
    *(bf16x8*)&d[i] = *(bf16x8*)h;
}

// ---------------------------------------------------------------------------
// RoPE cos/sin table: cst[si*32 + f] = (cos, sin) of tp[si] * theta^(-2f/64).
// ---------------------------------------------------------------------------
__global__ __launch_bounds__(256) void rope_tab(
    const int* __restrict__ tp, float2* __restrict__ cst)
{
    int idx = blockIdx.x * 256 + threadIdx.x;      // 65536 entries
    int si = idx >> 5;
    int f  = idx & 31;
    float pos = (float)tp[si];
    float freq = exp2f(-(float)(2 * f) * ROPE_L2F);
    float s, c;
    __sincosf(pos * freq, &s, &c);
    cst[idx] = make_float2(c, s);
}

// ---------------------------------------------------------------------------
// bf16 MFMA GEMM main loop (m97-style): 128x128 tile, 4 waves 2x2.
// TWO BK=32 k-steps double-buffered per barrier pair (round-6 win, ~20us).
// SWAP=0: acc[mt][nt] = mfma(a_h[mt], b_h[nt]) — M dim (regs, quad*4+r) =
//   token row, N dim (lanes, l16) = feature col; verified orientation.
// SWAP=1: acc[ft][tt] = mfma(b_h[ft], a_h[tt]) — transposed: M dim (regs)
//   = FEATURE, N dim (lanes) = TOKEN. Lets proj_qkv do RoPE pairing in-lane
//   (adjacent regs) with zero shuffles and 8B stores. Valid because a_h/b_h
//   fragments are loaded with identical per-lane geometry.
// Staging geometry/swizzle identical to the verified BK=32 version.
// ---------------------------------------------------------------------------
#define PROJ_PROLOGUE(SWAP)                                                  \
    __shared__ short As[2][128][32];                                         \
    __shared__ short Bs[2][128][32];                                         \
    const int m0 = blockIdx.y * 128;                                         \
    const int n0 = blockIdx.x * 128;                                         \
    const int tid = threadIdx.x;                                             \
    const int lane = tid & 63;                                               \
    const int wave = tid >> 6;                                               \
    const int quad = lane >> 4;                                              \
    const int l16 = lane & 15;                                               \
    const int wr = (wave >> 1) * 64;                                         \
    const int wc = (wave & 1) * 64;                                          \
    const int srow = wave * 32 + (lane >> 2);                                \
    const int schunk = (lane & 3) ^ ((lane >> 2) & 3);                       \
    const short* agp = &A[(size_t)(m0 + srow) * D_MODEL + schunk * 8];       \
    const short* bgp = &Bw[(size_t)(n0 + srow) * D_MODEL + schunk * 8];      \
    const int fchunk = quad ^ (l16 & 3);                                     \
    f32x4 acc[4][4] = {};                                                    \
    for (int k0 = 0; k0 < D_MODEL; k0 += 64) {                               \
        _Pragma("unroll")                                                    \
        for (int bb = 0; bb < 2; ++bb) {                                     \
            const short* ag = agp + bb * 32;                                 \
            const short* bg = bgp + bb * 32;                                 \
            load_lds16(ag, &As[bb][wave * 32][0]);                           \
            load_lds16(ag + 16 * D_MODEL, &As[bb][wave * 32 + 16][0]);       \
            load_lds16(bg, &Bs[bb][wave * 32][0]);                           \
            load_lds16(bg + 16 * D_MODEL, &Bs[bb][wave * 32 + 16][0]);       \
        }                                                                    \
        agp += 64; bgp += 64;                                                \
        __syncthreads();                                                     \
        _Pragma("unroll")                                                    \
        for (int bb = 0; bb < 2; ++bb) {                                     \
            bf16x8 a_h[4], b_h[4];                                           \
            _Pragma("unroll")                                                \
            for (int t = 0; t < 4; ++t) {                                    \
                a_h[t] = *(const bf16x8*)                                    \
                    &As[bb][wr + t * 16 + l16][fchunk * 8];                  \
                b_h[t] = *(const bf16x8*)                                    \
                    &Bs[bb][wc + t * 16 + l16][fchunk * 8];                  \
            }                                                                \
            _Pragma("unroll")                                                \
            for (int i = 0; i < 4; ++i)                                      \
                _Pragma("unroll")                                            \
                for (int j = 0; j < 4; ++j)                                  \
                    acc[i][j] = __builtin_amdgcn_mfma_f32_16x16x32_bf16(     \
                        (SWAP) ? b_h[i] : a_h[i],                            \
                        (SWAP) ? a_h[j] : b_h[j],                            \
                        acc[i][j], 0, 0, 0);                                 \
        }                                                                    \
        __syncthreads();                                                     \
    }

// ---------------------------------------------------------------------------
// Fused QKV projection: C = x (8192x1024) @ [Wq;Wk;Wv]^T (1024x3072).
// TRANSPOSED epilogue (SWAP=1): acc[ft][tt]; per lane, M-reg dim = 4
// consecutive FEATURES (quad*4+r), lane dim = TOKEN (l16). RoPE even/odd
// pairs are (reg0,reg1),(reg2,reg3) — no shuffles; cvt_pk packs; one
// uint2 (8B) store per (ft,tt) instead of 4 scalar 2B stores.
// ---------------------------------------------------------------------------
__global__ __launch_bounds__(256) void proj_qkv(
    const short* __restrict__ A, const short* __restrict__ Bw,
    const float2* __restrict__ cst,
    short* __restrict__ Qo, short* __restrict__ Ko, short* __restrict__ Vo)
{
    PROJ_PROLOGUE(1)

    const int which = n0 >> 10;                    // 0=Q 1=K 2=V
    short* __restrict__ outp = (which == 0) ? Qo : (which == 1) ? Ko : Vo;
    const float scale = (which == 0) ? QSCALE : 1.0f;
    const int nbase = n0 & (D_MODEL - 1);

#pragma unroll
    for (int ft = 0; ft < 4; ++ft) {
        const int colb = nbase + wc + ft * 16 + quad * 4;  // feature, 4-aligned
        const int head = colb >> 6;
        const int tloc = colb & 63;
#pragma unroll
        for (int tt = 0; tt < 4; ++tt) {
            const int row = m0 + wr + tt * 16 + l16;       // token
            const int bi = row >> 11;
            const int si = row & (S_LEN - 1);
            f32x4 v = acc[ft][tt];
            uint2 uu;
            if (which < 2) {
                float2 cs0 = cst[si * 32 + (tloc >> 1)];
                float2 cs1 = cst[si * 32 + (tloc >> 1) + 1];
                uu.x = cvt_pk_bf16((cs0.x * v[0] - cs0.y * v[1]) * scale,
                                   (cs0.y * v[0] + cs0.x * v[1]) * scale);
                uu.y = cvt_pk_bf16((cs1.x * v[2] - cs1.y * v[3]) * scale,
                                   (cs1.y * v[2] + cs1.x * v[3]) * scale);
            } else {
                uu.x = cvt_pk_bf16(v[0], v[1]);
                uu.y = cvt_pk_bf16(v[2], v[3]);
            }
            *(uint2*)&outp[(((size_t)bi * NH + head) * S_LEN + si) * DK +
                           tloc] = uu;
        }
    }
}

// ---------------------------------------------------------------------------
// Output projection: out = attnO (8192x1024) @ Wo^T, fp32 row-major.
// Standard orientation (SWAP=0): row=token (quad*4+r), col=feature (l16) —
// fp32 stores are already coalesced 64B/quad-row.
// ---------------------------------------------------------------------------
__global__ __launch_bounds__(256) void proj_out(
    const short* __restrict__ A, const short* __restrict__ Bw,
    float* __restrict__ outf)
{
    PROJ_PROLOGUE(0)

#pragma unroll
    for (int mt = 0; mt < 4; ++mt) {
#pragma unroll
        for (int r = 0; r < 4; ++r) {
            const int row = m0 + wr + mt * 16 + quad * 4 + r;
#pragma unroll
            for (int nt = 0; nt < 4; ++nt) {
                int col = n0 + wc + nt * 16 + l16;
                outf[(size_t)row * D_MODEL + col] = acc[mt][nt][r];
            }
        }
    }
}

// ---------------------------------------------------------------------------
// MFMA flash causal attention — ROUND-6 VERSION (verified 153us, twice).
// Round-5 AND round-9 both falsified thin-wave/high-occupancy variants
// (VGPR squeezed to 64/56 => remat chain; 40% occupancy but SLOWER).
// 2 fat waves/SIMD with reg-dbuf'd K is the local optimum for this dataflow.
// Structure: 4 waves x 32 q-rows, Bk=64, one barrier per TWO k-tiles
// (Vt 4-deep), K frags double-buffered in regs, lane-local defer-max
// (THR=8), lane-partial l reduced in epilogue, cvt_pk P-packing, balanced
// pairing (34 tiles/block uniform), XCD head-grouping (FETCH 24.7MB).
// ---------------------------------------------------------------------------
#define PADS 72

__global__ __launch_bounds__(256) void attn_bf16(
    const short* __restrict__ Q, const short* __restrict__ K,
    const short* __restrict__ V, short* __restrict__ O)
{
    __shared__ short Vt[4][64][PADS];  // V tiles transposed [d][k], 2 dbuf pairs
    __shared__ short Ps[128][PADS];    // P rows, wave-private

    const int bh   = blockIdx.x * 8 + (blockIdx.y >> 3);
    const int pair = blockIdx.y & 7;

    const int tid = threadIdx.x;
    const int wave = tid >> 6;
    const int lane = tid & 63;
    const int quad = lane >> 4;
    const int l16 = lane & 15;

    const short* Kb = K + (size_t)bh * S_LEN * DK;
    const short* Vb = V + (size_t)bh * S_LEN * DK;

    // V staging geometry (transpose via short2)
    const int kp2 = (tid & 31) * 2;
    const int db = (tid >> 5) * 8;

    const int bi = bh >> 4;
    const int head = bh & 15;

    for (int half = 0; half < 2; ++half) {
        const int bx = half ? pair : (15 - pair);
        const int qbase = bx * 128 + wave * 32;
        const int qlim = qbase + 31;

        // Q fragments straight from global (wave-private rows)
        bf16x8 Qf[2][2];
#pragma unroll
        for (int sub = 0; sub < 2; ++sub)
#pragma unroll
            for (int c = 0; c < 2; ++c)
                Qf[sub][c] = *(const bf16x8*)
                    &Q[((size_t)bh * S_LEN + qbase + sub * 16 + l16) * DK +
                       c * 32 + quad * 8];

        // preload tiles 0,1: V rows into regs, K frags into regs
        bf16x8 va0 = *(const bf16x8*)&Vb[(size_t)kp2 * DK + db];
        bf16x8 va1 = *(const bf16x8*)&Vb[(size_t)(kp2 + 1) * DK + db];
        bf16x8 vb0 = *(const bf16x8*)&Vb[(size_t)(64 + kp2) * DK + db];
        bf16x8 vb1 = *(const bf16x8*)&Vb[(size_t)(64 + kp2 + 1) * DK + db];
        bf16x8 Kf[2][4][2];   // [tile parity][kt][c]
#pragma unroll
        for (int par = 0; par < 2; ++par)
#pragma unroll
            for (int kt = 0; kt < 4; ++kt)
#pragma unroll
                for (int c = 0; c < 2; ++c)
                    Kf[par][kt][c] = *(const bf16x8*)
                        &Kb[(size_t)(par * 64 + kt * 16 + l16) * DK +
                            c * 32 + quad * 8];

        float m_i[2] = { -1e30f, -1e30f };
        float l_i[2] = { 0.0f, 0.0f };     // LANE-PARTIAL; reduced in epilogue
        f32x4 o[2][4] = {};

        const int ktiles = 2 * bx + 2;     // always even
        for (int tt = 0; tt < ktiles; tt += 2) {
            const int bufA = (tt & 2);     // {0,2,0,2,...}
            const int bufB = bufA | 1;

            // ---- commit both prefetched V tiles ----
#pragma unroll
            for (int i = 0; i < 8; ++i) {
                short2v pa; pa.x = va0[i]; pa.y = va1[i];
                *(short2v*)&Vt[bufA][db + i][kp2] = pa;
                short2v pb; pb.x = vb0[i]; pb.y = vb1[i];
                *(short2v*)&Vt[bufB][db + i][kp2] = pb;
            }
            __syncthreads();               // one barrier per 2 tiles

            // ---- prefetch V tiles tt+2, tt+3 ----
            if (tt + 2 < ktiles) {
                const short* vp = &Vb[(size_t)((tt + 2) * 64 + kp2) * DK + db];
                va0 = *(const bf16x8*)vp;
                va1 = *(const bf16x8*)(vp + DK);
                vp += (size_t)64 * DK;
                vb0 = *(const bf16x8*)vp;
                vb1 = *(const bf16x8*)(vp + DK);
            }

            // ================= two tiles =================
#pragma unroll
            for (int sel = 0; sel < 2; ++sel) {
                const int t  = tt + sel;
                const int k0 = t * 64;
                const int buf = sel ? bufB : bufA;
                if (k0 > qlim) continue;   // wave has no live q rows here

                // ---- S^T = K * Q^T ----
                f32x4 sT2[2][4];
#pragma unroll
                for (int sub = 0; sub < 2; ++sub) {
#pragma unroll
                    for (int kt = 0; kt < 4; ++kt) sT2[sub][kt] = f32x4{};
#pragma unroll
                    for (int c = 0; c < 2; ++c)
#pragma unroll
                        for (int kt = 0; kt < 4; ++kt)
                            sT2[sub][kt] =
                                __builtin_amdgcn_mfma_f32_16x16x32_bf16(
                                    Kf[sel][kt][c], Qf[sub][c],
                                    sT2[sub][kt], 0, 0, 0);
                }

                // Kf[sel] dead now -> prefetch tile t+2 into it (WAR)
                if (k0 + 128 <= qlim) {
#pragma unroll
                    for (int kt = 0; kt < 4; ++kt)
#pragma unroll
                        for (int c = 0; c < 2; ++c)
                            Kf[sel][kt][c] = *(const bf16x8*)
                                &Kb[(size_t)(k0 + 128 + kt * 16 + l16) * DK +
                                    c * 32 + quad * 8];
                }

#pragma unroll
                for (int sub = 0; sub < 2; ++sub) {
                    f32x4* sT = sT2[sub];
                    const int qg = qbase + sub * 16 + l16;
                    if (k0 + 63 > qbase + sub * 16) {   // causal mask needed
#pragma unroll
                        for (int kt = 0; kt < 4; ++kt)
#pragma unroll
                            for (int r = 0; r < 4; ++r)
                                if (k0 + kt * 16 + quad * 4 + r > qg)
                                    sT[kt][r] = -1e30f;
                    }

                    // per-lane max (no cross-lane in common path)
                    float tmax = fmaxf(
                        fmaxf(fmaxf(sT[0][0], sT[0][1]),
                              fmaxf(sT[0][2], sT[0][3])),
                        fmaxf(fmaxf(fmaxf(sT[1][0], sT[1][1]),
                                    fmaxf(sT[1][2], sT[1][3])),
                              fmaxf(fmaxf(fmaxf(sT[2][0], sT[2][1]),
                                          fmaxf(sT[2][2], sT[2][3])),
                                    fmaxf(fmaxf(sT[3][0], sT[3][1]),
                                          fmaxf(sT[3][2], sT[3][3])))));
                    // defer-max: rescale only if some lane exceeds m+8
                    if (!__all(tmax <= m_i[sub] + 8.0f)) {
                        float tm = fmaxf(tmax, __shfl_xor(tmax, 16));
                        tm = fmaxf(tm, __shfl_xor(tm, 32));
                        float mnew = fmaxf(m_i[sub], tm);
                        float alpha = exp2f(m_i[sub] - mnew);
                        m_i[sub] = mnew;
                        l_i[sub] *= alpha;
#pragma unroll
                        for (int dt = 0; dt < 4; ++dt) {
                            o[sub][dt][0] *= alpha; o[sub][dt][1] *= alpha;
                            o[sub][dt][2] *= alpha; o[sub][dt][3] *= alpha;
                        }
                    }
                    const float mn = m_i[sub];
                    float rs = 0.0f;
                    const int prow = wave * 32 + sub * 16 + l16;
#pragma unroll
                    for (int kt = 0; kt < 4; ++kt) {
                        float p0 = exp2f(sT[kt][0] - mn);
                        float p1 = exp2f(sT[kt][1] - mn);
                        float p2 = exp2f(sT[kt][2] - mn);
                        float p3 = exp2f(sT[kt][3] - mn);
                        rs += (p0 + p1) + (p2 + p3);
                        uint2 uu;
                        uu.x = cvt_pk_bf16(p0, p1);
                        uu.y = cvt_pk_bf16(p2, p3);
                        *(uint2*)&Ps[prow][kt * 16 + quad * 4] = uu;
                    }
                    l_i[sub] += rs;        // lane-partial accumulate
                }

                // ---- O^T += V^T P^T ----
                bf16x8 Pf[2][2];
#pragma unroll
                for (int sub = 0; sub < 2; ++sub)
#pragma unroll
                    for (int c = 0; c < 2; ++c)
                        Pf[sub][c] = *(const bf16x8*)
                            &Ps[wave * 32 + sub * 16 + l16][c * 32 + quad * 8];
#pragma unroll
                for (int c = 0; c < 2; ++c)
#pragma unroll
                    for (int dt = 0; dt < 4; ++dt) {
                        bf16x8 av = *(const bf16x8*)
                            &Vt[buf][dt * 16 + l16][c * 32 + quad * 8];
#pragma unroll
                        for (int sub = 0; sub < 2; ++sub)
                            o[sub][dt] =
                                __builtin_amdgcn_mfma_f32_16x16x32_bf16(
                                    av, Pf[sub][c], o[sub][dt], 0, 0, 0);
                    }
            }
        }
        __syncthreads();   // protect Vt bufs before next half's first commit

        // ---- epilogue: reduce lane-partial l, normalize, write bf16 ----
#pragma unroll
        for (int sub = 0; sub < 2; ++sub) {
            float lt = l_i[sub];
            lt += __shfl_xor(lt, 16);
            lt += __shfl_xor(lt, 32);
            const float linv = 1.0f / lt;
            const int q = qbase + sub * 16 + l16;
            short* ob = &O[((size_t)bi * S_LEN + q) * D_MODEL + head * DK];
#pragma unroll
            for (int dt = 0; dt < 4; ++dt) {
                short4v h;
                h.x = f2bf(o[sub][dt][0] * linv);
                h.y = f2bf(o[sub][dt][1] * linv);
                h.z = f2bf(o[sub][dt][2] * linv);
                h.w = f2bf(o[sub][dt][3] * linv);
                *(short4v*)&ob[dt * 16 + quad * 4] = h;
            }
        }
    }
}

extern "C" void kernel_launch(void* const* d_in, const int* in_sizes, int n_in,
                              void* d_out, int out_size, void* d_ws, size_t ws_size,
                              hipStream_t stream) {
    const float* x  = (const float*)d_in[0];
    const float* Wq = (const float*)d_in[1];
    const float* Wk = (const float*)d_in[2];
    const float* Wv = (const float*)d_in[3];
    const float* Wo = (const float*)d_in[4];
    const int*   tp = (const int*)d_in[5];
    float* out = (float*)d_out;

    const int n  = BATCH * S_LEN * D_MODEL;       // 8388608
    const int nw = D_MODEL * D_MODEL;             // 1048576
    short* sw   = (short*)d_ws;
    short* xbf  = sw;
    short* Qbf  = sw + (size_t)n;
    short* Kbf  = sw + (size_t)2 * n;
    short* Vbf  = sw + (size_t)3 * n;
    short* Obf  = sw + (size_t)4 * n;
    short* Wqbf = sw + (size_t)5 * n;             // Wq;Wk;Wv contiguous (3072x1024)
    short* Wobf = Wqbf + (size_t)3 * nw;
    // RoPE table overlaid on Obf (dead until attn writes it; stream order
    // guarantees rope_tab -> proj_qkv(read) -> attn(overwrite) -> proj_out).
    float2* cst = (float2*)Obf;                   // 512 KB of the 16.8 MB region

    dim3 blk(256);
    conv_bf16<<<n / (256 * 8), blk, 0, stream>>>(x, xbf, n);
    dim3 gw(nw / (256 * 8), 4);
    conv_w4<<<gw, blk, 0, stream>>>(Wq, Wk, Wv, Wo, Wqbf);
    rope_tab<<<(S_LEN * 32) / 256, blk, 0, stream>>>(tp, cst);

    dim3 gqkv(3 * D_MODEL / 128, (BATCH * S_LEN) / 128);   // (24, 64)
    proj_qkv<<<gqkv, blk, 0, stream>>>(xbf, Wqbf, cst, Qbf, Kbf, Vbf);

    dim3 gattn(8, BATCH * NH);                             // paired causal
    attn_bf16<<<gattn, blk, 0, stream>>>(Qbf, Kbf, Vbf, Obf);

    dim3 gout(D_MODEL / 128, (BATCH * S_LEN) / 128);       // (8, 64)
    proj_out<<<gout, blk, 0, stream>>>(Obf, Wobf, out);
}

// Round 12
// 343.773 us; speedup vs baseline: 1.1277x; 1.0005x over previous
//
#include <hip/hip_runtime.h>
#include <math.h>

#define S_LEN 2048
#define D_MODEL 1024
#define NH 16
#define DK 64
#define BATCH 4

// log2(10000)/64
#define ROPE_L2F 0.20762050593046014f
// 0.125 * log2(e): folds 1/sqrt(dk) and exp->exp2 conversion into Q
#define QSCALE 0.18033688011112042f

typedef __attribute__((ext_vector_type(8))) short bf16x8;
typedef __attribute__((ext_vector_type(4))) short short4v;
typedef __attribute__((ext_vector_type(2))) short short2v;
typedef __attribute__((ext_vector_type(4))) float f32x4;

__device__ inline short f2bf(float f) {            // RNE fp32 -> bf16 bits
    unsigned u = __builtin_bit_cast(unsigned, f);
    unsigned r = u + 0x7FFFu + ((u >> 16) & 1u);
    return (short)(r >> 16);
}

// packed fp32x2 -> bf16x2 (RNE), single VALU op
__device__ inline unsigned cvt_pk_bf16(float lo, float hi) {
    unsigned r;
    asm("v_cvt_pk_bf16_f32 %0, %1, %2" : "=v"(r) : "v"(lo), "v"(hi));
    return r;
}

// async global->LDS, 16B per lane; lds base must be wave-uniform.
__device__ inline void load_lds16(const void* g, void* l) {
    __builtin_amdgcn_global_load_lds(
        (const __attribute__((address_space(1))) unsigned int*)g,
        (__attribute__((address_space(3))) unsigned int*)l, 16, 0, 0);
}

// ---------------------------------------------------------------------------
// One-time fp32 -> bf16 conversions.
// ---------------------------------------------------------------------------
__global__ __launch_bounds__(256) void conv_bf16(
    const float* __restrict__ src, short* __restrict__ dst, int n)
{
    int i = (blockIdx.x * 256 + threadIdx.x) * 8;
    if (i >= n) return;
    float4 a = *(const float4*)&src[i];
    float4 b = *(const float4*)&src[i + 4];
    short h[8] = { f2bf(a.x), f2bf(a.y), f2bf(a.z), f2bf(a.w),
                   f2bf(b.x), f2bf(b.y), f2bf(b.z), f2bf(b.w) };
    *(bf16x8*)&dst[i] = *(bf16x8*)h;
}

__global__ __launch_bounds__(256) void conv_w4(
    const float* __restrict__ Wq, const float* __restrict__ Wk,
    const float* __restrict__ Wv, const float* __restrict__ Wo,
    short* __restrict__ dst)
{
    const float* srcs[4] = { Wq, Wk, Wv, Wo };
    const float* s = srcs[blockIdx.y];
    short* d = dst + (size_t)blockIdx.y * (D_MODEL * D_MODEL);
    int i = (blockIdx.x * 256 + threadIdx.x) * 8;
    float4 a = *(const float4*)&s[i];
    float4 b = *(const float4*)&s[i + 4];
    short h[8] = { f2bf(a.x), f2bf(a.y), f2bf(a.z), f2bf(a.w),
                   f2bf(b.x), f2bf(b.y), f2bf(b.z), f2bf(b.w) };
    *(bf16x8*)&d[i] = *(bf16x8*)h;
}

// ---------------------------------------------------------------------------
// RoPE cos/sin table: cst[si*32 + f] = (cos, sin) of tp[si] * theta^(-2f/64).
// ---------------------------------------------------------------------------
__global__ __launch_bounds__(256) void rope_tab(
    const int* __restrict__ tp, float2* __restrict__ cst)
{
    int idx = blockIdx.x * 256 + threadIdx.x;      // 65536 entries
    int si = idx >> 5;
    int f  = idx & 31;
    float pos = (float)tp[si];
    float freq = exp2f(-(float)(2 * f) * ROPE_L2F);
    float s, c;
    __sincosf(pos * freq, &s, &c);
    cst[idx] = make_float2(c, s);
}

// ---------------------------------------------------------------------------
// bf16 MFMA GEMM main loop (m97-style): 128x128 tile, 4 waves 2x2.
// ROUND 12: 2-PHASE PIPELINE (T3 minimum recipe, m248v2/m230-V0). Old
// structure staged then IMMEDIATELY barriered — the vmcnt(0) drain ate the
// full L2 load latency with no compute in flight. Now: prologue stages
// buf 0; each BK=32 iteration (a) issues next chunk's 4 global_load_lds
// into buf^1 FIRST, (b) ds_read+16 MFMA from buf, (c) ONE __syncthreads.
// Load latency hides under compute; barrier at end of iter i separates all
// reads of As[i&1] from iter i+1's overwrite (dbuf safe, 1 barrier/step).
// SWAP=0: acc[mt][nt]=mfma(a_h,b_h) — M regs = token row, N lanes = feature.
// SWAP=1: acc[ft][tt]=mfma(b_h,a_h) — transposed (feature on regs) for the
// shuffle-free RoPE epilogue (round-11 win, ~22us).
// Staging geometry/swizzle per buffer identical to the verified version.
// ---------------------------------------------------------------------------
#define PROJ_STAGE(BUF)                                                      \
    {                                                                        \
        load_lds16(agp, &As[BUF][wave * 32][0]);                             \
        load_lds16(agp + 16 * D_MODEL, &As[BUF][wave * 32 + 16][0]);         \
        load_lds16(bgp, &Bs[BUF][wave * 32][0]);                             \
        load_lds16(bgp + 16 * D_MODEL, &Bs[BUF][wave * 32 + 16][0]);         \
        agp += 32; bgp += 32;                                                \
    }

#define PROJ_PROLOGUE(SWAP)                                                  \
    __shared__ short As[2][128][32];                                         \
    __shared__ short Bs[2][128][32];                                         \
    const int m0 = blockIdx.y * 128;                                         \
    const int n0 = blockIdx.x * 128;                                         \
    const int tid = threadIdx.x;                                             \
    const int lane = tid & 63;                                               \
    const int wave = tid >> 6;                                               \
    const int quad = lane >> 4;                                              \
    const int l16 = lane & 15;                                               \
    const int wr = (wave >> 1) * 64;                                         \
    const int wc = (wave & 1) * 64;                                          \
    const int srow = wave * 32 + (lane >> 2);                                \
    const int schunk = (lane & 3) ^ ((lane >> 2) & 3);                       \
    const short* agp = &A[(size_t)(m0 + srow) * D_MODEL + schunk * 8];       \
    const short* bgp = &Bw[(size_t)(n0 + srow) * D_MODEL + schunk * 8];      \
    const int fchunk = quad ^ (l16 & 3);                                     \
    f32x4 acc[4][4] = {};                                                    \
    PROJ_STAGE(0)                                                            \
    __syncthreads();                                                         \
    _Pragma("unroll 2")                                                      \
    for (int k0 = 0; k0 < D_MODEL; k0 += 32) {                               \
        const int cur = (k0 >> 5) & 1;                                       \
        if (k0 + 32 < D_MODEL) PROJ_STAGE(cur ^ 1)                           \
        bf16x8 a_h[4], b_h[4];                                               \
        _Pragma("unroll")                                                    \
        for (int t = 0; t < 4; ++t) {                                        \
            a_h[t] = *(const bf16x8*)                                        \
                &As[cur][wr + t * 16 + l16][fchunk * 8];                     \
            b_h[t] = *(const bf16x8*)                                        \
                &Bs[cur][wc + t * 16 + l16][fchunk * 8];                     \
        }                                                                    \
        _Pragma("unroll")                                                    \
        for (int i = 0; i < 4; ++i)                                          \
            _Pragma("unroll")                                                \
            for (int j = 0; j < 4; ++j)                                      \
                acc[i][j] = __builtin_amdgcn_mfma_f32_16x16x32_bf16(         \
                    (SWAP) ? b_h[i] : a_h[i],                                \
                    (SWAP) ? a_h[j] : b_h[j],                                \
                    acc[i][j], 0, 0, 0);                                     \
        __syncthreads();                                                     \
    }

// ---------------------------------------------------------------------------
// Fused QKV projection: C = x (8192x1024) @ [Wq;Wk;Wv]^T (1024x3072).
// TRANSPOSED epilogue (SWAP=1): acc[ft][tt]; per lane, M-reg dim = 4
// consecutive FEATURES (quad*4+r), lane dim = TOKEN (l16). RoPE even/odd
// pairs are (reg0,reg1),(reg2,reg3) — no shuffles; cvt_pk packs; one
// uint2 (8B) store per (ft,tt) instead of 4 scalar 2B stores.
// ---------------------------------------------------------------------------
__global__ __launch_bounds__(256) void proj_qkv(
    const short* __restrict__ A, const short* __restrict__ Bw,
    const float2* __restrict__ cst,
    short* __restrict__ Qo, short* __restrict__ Ko, short* __restrict__ Vo)
{
    PROJ_PROLOGUE(1)

    const int which = n0 >> 10;                    // 0=Q 1=K 2=V
    short* __restrict__ outp = (which == 0) ? Qo : (which == 1) ? Ko : Vo;
    const float scale = (which == 0) ? QSCALE : 1.0f;
    const int nbase = n0 & (D_MODEL - 1);

#pragma unroll
    for (int ft = 0; ft < 4; ++ft) {
        const int colb = nbase + wc + ft * 16 + quad * 4;  // feature, 4-aligned
        const int head = colb >> 6;
        const int tloc = colb & 63;
#pragma unroll
        for (int tt = 0; tt < 4; ++tt) {
            const int row = m0 + wr + tt * 16 + l16;       // token
            const int bi = row >> 11;
            const int si = row & (S_LEN - 1);
            f32x4 v = acc[ft][tt];
            uint2 uu;
            if (which < 2) {
                float2 cs0 = cst[si * 32 + (tloc >> 1)];
                float2 cs1 = cst[si * 32 + (tloc >> 1) + 1];
                uu.x = cvt_pk_bf16((cs0.x * v[0] - cs0.y * v[1]) * scale,
                                   (cs0.y * v[0] + cs0.x * v[1]) * scale);
                uu.y = cvt_pk_bf16((cs1.x * v[2] - cs1.y * v[3]) * scale,
                                   (cs1.y * v[2] + cs1.x * v[3]) * scale);
            } else {
                uu.x = cvt_pk_bf16(v[0], v[1]);
                uu.y = cvt_pk_bf16(v[2], v[3]);
            }
            *(uint2*)&outp[(((size_t)bi * NH + head) * S_LEN + si) * DK +
                           tloc] = uu;
        }
    }
}

// ---------------------------------------------------------------------------
// Output projection: out = attnO (8192x1024) @ Wo^T, fp32 row-major.
// Standard orientation (SWAP=0): row=token (quad*4+r), col=feature (l16) —
// fp32 stores are already coalesced 64B/quad-row.
// ---------------------------------------------------------------------------
__global__ __launch_bounds__(256) void proj_out(
    const short* __restrict__ A, const short* __restrict__ Bw,
    float* __restrict__ outf)
{
    PROJ_PROLOGUE(0)

#pragma unroll
    for (int mt = 0; mt < 4; ++mt) {
#pragma unroll
        for (int r = 0; r < 4; ++r) {
            const int row = m0 + wr + mt * 16 + quad * 4 + r;
#pragma unroll
            for (int nt = 0; nt < 4; ++nt) {
                int col = n0 + wc + nt * 16 + l16;
                outf[(size_t)row * D_MODEL + col] = acc[mt][nt][r];
            }
        }
    }
}

// ---------------------------------------------------------------------------
// MFMA flash causal attention — ROUND-6 VERSION (verified ~154us, 3 times).
// Round-5 AND round-9 both falsified thin-wave/high-occupancy variants
// (VGPR squeezed to 64/56 => remat chain; 40% occupancy but SLOWER).
// 2 fat waves/SIMD with reg-dbuf'd K is the local optimum for this dataflow.
// Structure: 4 waves x 32 q-rows, Bk=64, one barrier per TWO k-tiles
// (Vt 4-deep), K frags double-buffered in regs, lane-local defer-max
// (THR=8), lane-partial l reduced in epilogue, cvt_pk P-packing, balanced
// pairing (34 tiles/block uniform), XCD head-grouping (FETCH 24.7MB).
// ---------------------------------------------------------------------------
#define PADS 72

__global__ __launch_bounds__(256) void attn_bf16(
    const short* __restrict__ Q, const short* __restrict__ K,
    const short* __restrict__ V, short* __restrict__ O)
{
    __shared__ short Vt[4][64][PADS];  // V tiles transposed [d][k], 2 dbuf pairs
    __shared__ short Ps[128][PADS];    // P rows, wave-private

    const int bh   = blockIdx.x * 8 + (blockIdx.y >> 3);
    const int pair = blockIdx.y & 7;

    const int tid = threadIdx.x;
    const int wave = tid >> 6;
    const int lane = tid & 63;
    const int quad = lane >> 4;
    const int l16 = lane & 15;

    const short* Kb = K + (size_t)bh * S_LEN * DK;
    const short* Vb = V + (size_t)bh * S_LEN * DK;

    // V staging geometry (transpose via short2)
    const int kp2 = (tid & 31) * 2;
    const int db = (tid >> 5) * 8;

    const int bi = bh >> 4;
    const int head = bh & 15;

    for (int half = 0; half < 2; ++half) {
        const int bx = half ? pair : (15 - pair);
        const int qbase = bx * 128 + wave * 32;
        const int qlim = qbase + 31;

        // Q fragments straight from global (wave-private rows)
        bf16x8 Qf[2][2];
#pragma unroll
        for (int sub = 0; sub < 2; ++sub)
#pragma unroll
            for (int c = 0; c < 2; ++c)
                Qf[sub][c] = *(const bf16x8*)
                    &Q[((size_t)bh * S_LEN + qbase + sub * 16 + l16) * DK +
                       c * 32 + quad * 8];

        // preload tiles 0,1: V rows into regs, K frags into regs
        bf16x8 va0 = *(const bf16x8*)&Vb[(size_t)kp2 * DK + db];
        bf16x8 va1 = *(const bf16x8*)&Vb[(size_t)(kp2 + 1) * DK + db];
        bf16x8 vb0 = *(const bf16x8*)&Vb[(size_t)(64 + kp2) * DK + db];
        bf16x8 vb1 = *(const bf16x8*)&Vb[(size_t)(64 + kp2 + 1) * DK + db];
        bf16x8 Kf[2][4][2];   // [tile parity][kt][c]
#pragma unroll
        for (int par = 0; par < 2; ++par)
#pragma unroll
            for (int kt = 0; kt < 4; ++kt)
#pragma unroll
                for (int c = 0; c < 2; ++c)
                    Kf[par][kt][c] = *(const bf16x8*)
                        &Kb[(size_t)(par * 64 + kt * 16 + l16) * DK +
                            c * 32 + quad * 8];

        float m_i[2] = { -1e30f, -1e30f };
        float l_i[2] = { 0.0f, 0.0f };     // LANE-PARTIAL; reduced in epilogue
        f32x4 o[2][4] = {};

        const int ktiles = 2 * bx + 2;     // always even
        for (int tt = 0; tt < ktiles; tt += 2) {
            const int bufA = (tt & 2);     // {0,2,0,2,...}
            const int bufB = bufA | 1;

            // ---- commit both prefetched V tiles ----
#pragma unroll
            for (int i = 0; i < 8; ++i) {
                short2v pa; pa.x = va0[i]; pa.y = va1[i];
                *(short2v*)&Vt[bufA][db + i][kp2] = pa;
                short2v pb; pb.x = vb0[i]; pb.y = vb1[i];
                *(short2v*)&Vt[bufB][db + i][kp2] = pb;
            }
            __syncthreads();               // one barrier per 2 tiles

            // ---- prefetch V tiles tt+2, tt+3 ----
            if (tt + 2 < ktiles) {
                const short* vp = &Vb[(size_t)((tt + 2) * 64 + kp2) * DK + db];
                va0 = *(const bf16x8*)vp;
                va1 = *(const bf16x8*)(vp + DK);
                vp += (size_t)64 * DK;
                vb0 = *(const bf16x8*)vp;
                vb1 = *(const bf16x8*)(vp + DK);
            }

            // ================= two tiles =================
#pragma unroll
            for (int sel = 0; sel < 2; ++sel) {
                const int t  = tt + sel;
                const int k0 = t * 64;
                const int buf = sel ? bufB : bufA;
                if (k0 > qlim) continue;   // wave has no live q rows here

                // ---- S^T = K * Q^T ----
                f32x4 sT2[2][4];
#pragma unroll
                for (int sub = 0; sub < 2; ++sub) {
#pragma unroll
                    for (int kt = 0; kt < 4; ++kt) sT2[sub][kt] = f32x4{};
#pragma unroll
                    for (int c = 0; c < 2; ++c)
#pragma unroll
                        for (int kt = 0; kt < 4; ++kt)
                            sT2[sub][kt] =
                                __builtin_amdgcn_mfma_f32_16x16x32_bf16(
                                    Kf[sel][kt][c], Qf[sub][c],
                                    sT2[sub][kt], 0, 0, 0);
                }

                // Kf[sel] dead now -> prefetch tile t+2 into it (WAR)
                if (k0 + 128 <= qlim) {
#pragma unroll
                    for (int kt = 0; kt < 4; ++kt)
#pragma unroll
                        for (int c = 0; c < 2; ++c)
                            Kf[sel][kt][c] = *(const bf16x8*)
                                &Kb[(size_t)(k0 + 128 + kt * 16 + l16) * DK +
                                    c * 32 + quad * 8];
                }

#pragma unroll
                for (int sub = 0; sub < 2; ++sub) {
                    f32x4* sT = sT2[sub];
                    const int qg = qbase + sub * 16 + l16;
                    if (k0 + 63 > qbase + sub * 16) {   // causal mask needed
#pragma unroll
                        for (int kt = 0; kt < 4; ++kt)
#pragma unroll
                            for (int r = 0; r < 4; ++r)
                                if (k0 + kt * 16 + quad * 4 + r > qg)
                                    sT[kt][r] = -1e30f;
                    }

                    // per-lane max (no cross-lane in common path)
                    float tmax = fmaxf(
                        fmaxf(fmaxf(sT[0][0], sT[0][1]),
                              fmaxf(sT[0][2], sT[0][3])),
                        fmaxf(fmaxf(fmaxf(sT[1][0], sT[1][1]),
                                    fmaxf(sT[1][2], sT[1][3])),
                              fmaxf(fmaxf(fmaxf(sT[2][0], sT[2][1]),
                                          fmaxf(sT[2][2], sT[2][3])),
                                    fmaxf(fmaxf(sT[3][0], sT[3][1]),
                                          fmaxf(sT[3][2], sT[3][3])))));
                    // defer-max: rescale only if some lane exceeds m+8
                    if (!__all(tmax <= m_i[sub] + 8.0f)) {
                        float tm = fmaxf(tmax, __shfl_xor(tmax, 16));
                        tm = fmaxf(tm, __shfl_xor(tm, 32));
                        float mnew = fmaxf(m_i[sub], tm);
                        float alpha = exp2f(m_i[sub] - mnew);
                        m_i[sub] = mnew;
                        l_i[sub] *= alpha;
#pragma unroll
                        for (int dt = 0; dt < 4; ++dt) {
                            o[sub][dt][0] *= alpha; o[sub][dt][1] *= alpha;
                            o[sub][dt][2] *= alpha; o[sub][dt][3] *= alpha;
                        }
                    }
                    const float mn = m_i[sub];
                    float rs = 0.0f;
                    const int prow = wave * 32 + sub * 16 + l16;
#pragma unroll
                    for (int kt = 0; kt < 4; ++kt) {
                        float p0 = exp2f(sT[kt][0] - mn);
                        float p1 = exp2f(sT[kt][1] - mn);
                        float p2 = exp2f(sT[kt][2] - mn);
                        float p3 = exp2f(sT[kt][3] - mn);
                        rs += (p0 + p1) + (p2 + p3);
                        uint2 uu;
                        uu.x = cvt_pk_bf16(p0, p1);
                        uu.y = cvt_pk_bf16(p2, p3);
                        *(uint2*)&Ps[prow][kt * 16 + quad * 4] = uu;
                    }
                    l_i[sub] += rs;        // lane-partial accumulate
                }

                // ---- O^T += V^T P^T ----
                bf16x8 Pf[2][2];
#pragma unroll
                for (int sub = 0; sub < 2; ++sub)
#pragma unroll
                    for (int c = 0; c < 2; ++c)
                        Pf[sub][c] = *(const bf16x8*)
                            &Ps[wave * 32 + sub * 16 + l16][c * 32 + quad * 8];
#pragma unroll
                for (int c = 0; c < 2; ++c)
#pragma unroll
                    for (int dt = 0; dt < 4; ++dt) {
                        bf16x8 av = *(const bf16x8*)
                            &Vt[buf][dt * 16 + l16][c * 32 + quad * 8];
#pragma unroll
                        for (int sub = 0; sub < 2; ++sub)
                            o[sub][dt] =
                                __builtin_amdgcn_mfma_f32_16x16x32_bf16(
                                    av, Pf[sub][c], o[sub][dt], 0, 0, 0);
                    }
            }
        }
        __syncthreads();   // protect Vt bufs before next half's first commit

        // ---- epilogue: reduce lane-partial l, normalize, write bf16 ----
#pragma unroll
        for (int sub = 0; sub < 2; ++sub) {
            float lt = l_i[sub];
            lt += __shfl_xor(lt, 16);
            lt += __shfl_xor(lt, 32);
            const float linv = 1.0f / lt;
            const int q = qbase + sub * 16 + l16;
            short* ob = &O[((size_t)bi * S_LEN + q) * D_MODEL + head * DK];
#pragma unroll
            for (int dt = 0; dt < 4; ++dt) {
                short4v h;
                h.x = f2bf(o[sub][dt][0] * linv);
                h.y = f2bf(o[sub][dt][1] * linv);
                h.z = f2bf(o[sub][dt][2] * linv);
                h.w = f2bf(o[sub][dt][3] * linv);
                *(short4v*)&ob[dt * 16 + quad * 4] = h;
            }
        }
    }
}

extern "C" void kernel_launch(void* const* d_in, const int* in_sizes, int n_in,
                              void* d_out, int out_size, void* d_ws, size_t ws_size,
                              hipStream_t stream) {
    const float* x  = (const float*)d_in[0];
    const float* Wq = (const float*)d_in[1];
    const float* Wk = (const float*)d_in[2];
    const float* Wv = (const float*)d_in[3];
    const float* Wo = (const float*)d_in[4];
    const int*   tp = (const int*)d_in[5];
    float* out = (float*)d_out;

    const int n  = BATCH * S_LEN * D_MODEL;       // 8388608
    const int nw = D_MODEL * D_MODEL;             // 1048576
    short* sw   = (short*)d_ws;
    short* xbf  = sw;
    short* Qbf  = sw + (size_t)n;
    short* Kbf  = sw + (size_t)2 * n;
    short* Vbf  = sw + (size_t)3 * n;
    short* Obf  = sw + (size_t)4 * n;
    short* Wqbf = sw + (size_t)5 * n;             // Wq;Wk;Wv contiguous (3072x1024)
    short* Wobf = Wqbf + (size_t)3 * nw;
    // RoPE table overlaid on Obf (dead until attn writes it; stream order
    // guarantees rope_tab -> proj_qkv(read) -> attn(overwrite) -> proj_out).
    float2* cst = (float2*)Obf;                   // 512 KB of the 16.8 MB region

    dim3 blk(256);
    conv_bf16<<<n / (256 * 8), blk, 0, stream>>>(x, xbf, n);
    dim3 gw(nw / (256 * 8), 4);
    conv_w4<<<gw, blk, 0, stream>>>(Wq, Wk, Wv, Wo, Wqbf);
    rope_tab<<<(S_LEN * 32) / 256, blk, 0, stream>>>(tp, cst);

    dim3 gqkv(3 * D_MODEL / 128, (BATCH * S_LEN) / 128);   // (24, 64)
    proj_qkv<<<gqkv, blk, 0, stream>>>(xbf, Wqbf, cst, Qbf, Kbf, Vbf);

    dim3 gattn(8, BATCH * NH);                             // paired causal
    attn_bf16<<<gattn, blk, 0, stream>>>(Qbf, Kbf, Vbf, Obf);

    dim3 gout(D_MODEL / 128, (BATCH * S_LEN) / 128);       // (8, 64)
    proj_out<<<gout, blk, 0, stream>>>(Obf, Wobf, out);
}